// Round 15
// baseline (95.492 us; speedup 1.0000x reference)
//
#include <hip/hip_runtime.h>
#include <hip/hip_bf16.h>

#define N_FEAT 128
#define N_CLS 64
#define MAXD 64   // bucket capacity; true max in-deg ~40 for Binomial(800K,1/50K)

// 0) zero dense degree counters + overflow count (~200KB, ~1us)
__global__ __launch_bounds__(256) void k_zero(int4* __restrict__ p, int n4,
                                              int* __restrict__ ovf_cnt) {
    int i = blockIdx.x * blockDim.x + threadIdx.x;
    if (i < n4) p[i] = make_int4(0, 0, 0, 0);
    if (blockIdx.x == 0 && threadIdx.x == 0) *ovf_cnt = 0;
}

// 1) FUSED: blocks [0, gemm_blocks) = GEMM Ybf = bf16(X @ W) (wave-uniform W cols
//    -> s_load K$ broadcast). Remaining blocks = rank (atomic histogram, 2/thread).
__global__ __launch_bounds__(256) void k_fused1(
    const float* __restrict__ X, const float* __restrict__ W, ushort* __restrict__ Ybf, int n,
    const int* __restrict__ dst, int ne, int* __restrict__ deg, int* __restrict__ rank,
    int gemm_blocks) {
    int bid = blockIdx.x;
    if (bid < gemm_blocks) {
        int lane = threadIdx.x & 63;
        int q = __builtin_amdgcn_readfirstlane(threadIdx.x >> 6);  // wave 0..3
        int cq = q * 16;
        int node = bid * 64 + lane;
        if (node >= n) return;

        float acc[16];
#pragma unroll
        for (int c = 0; c < 16; ++c) acc[c] = 0.f;

        const float* xrow = X + (size_t)node * N_FEAT;
        const float* wq = W + cq;
        for (int k4 = 0; k4 < N_FEAT; k4 += 4) {
            float4 xv = *(const float4*)(xrow + k4);
#pragma unroll
            for (int j = 0; j < 4; ++j) {
                float xj = (j == 0) ? xv.x : (j == 1) ? xv.y : (j == 2) ? xv.z : xv.w;
                const float* wrow = wq + (size_t)(k4 + j) * N_CLS;  // wave-uniform
#pragma unroll
                for (int c = 0; c < 16; c += 4) {
                    float4 wv = *(const float4*)(wrow + c);
                    acc[c + 0] = fmaf(xj, wv.x, acc[c + 0]);
                    acc[c + 1] = fmaf(xj, wv.y, acc[c + 1]);
                    acc[c + 2] = fmaf(xj, wv.z, acc[c + 2]);
                    acc[c + 3] = fmaf(xj, wv.w, acc[c + 3]);
                }
            }
        }

        // RNE-convert 16 fp32 -> bf16, pack to 2x uint4, store 32B
        uint u[8];
#pragma unroll
        for (int h = 0; h < 8; ++h) {
            __hip_bfloat16 lo = __float2bfloat16(acc[2 * h]);
            __hip_bfloat16 hi = __float2bfloat16(acc[2 * h + 1]);
            ushort ulo = *(ushort*)&lo;
            ushort uhi = *(ushort*)&hi;
            u[h] = ((uint)uhi << 16) | ulo;
        }
        ushort* yrow = Ybf + (size_t)node * N_CLS + cq;
        *(uint4*)(yrow + 0) = make_uint4(u[0], u[1], u[2], u[3]);
        *(uint4*)(yrow + 8) = make_uint4(u[4], u[5], u[6], u[7]);
    } else {
        int e2 = ((bid - gemm_blocks) * 256 + threadIdx.x) * 2;
        if (e2 + 1 < ne) {
            int2 d = *(const int2*)(dst + e2);
            int p0 = atomicAdd(&deg[d.x], 1);  // two independent chains
            int p1 = atomicAdd(&deg[d.y], 1);
            *(int2*)(rank + e2) = make_int2(p0, p1);
        } else if (e2 < ne) {
            rank[e2] = atomicAdd(&deg[dst[e2]], 1);
        }
    }
}

// 2) scatter (no atomics in the hot path): slot[dst*MAXD+rank] = src
__global__ __launch_bounds__(256) void k_scat(const int* __restrict__ src,
                                              const int* __restrict__ dst,
                                              const int* __restrict__ rank, int ne,
                                              int* __restrict__ slot, int* __restrict__ ovf,
                                              int* __restrict__ ovf_cnt) {
    int e2 = (blockIdx.x * 256 + threadIdx.x) * 2;
#pragma unroll
    for (int j = 0; j < 2; ++j) {
        int i = e2 + j;
        if (i < ne) {
            int p = rank[i];
            if (p < MAXD) {
                slot[(size_t)dst[i] * MAXD + p] = src[i];
            } else {
                ovf[atomicAdd(ovf_cnt, 1) & 4095] = i;  // never expected; gutter
            }
        }
    }
}

// 3) wave-per-dst gather over buckets, bf16 Y rows (128B/row), on-the-fly rsqrt
//    from dense deg (200KB, L2-resident). Owner-wave folds any overflow edges in
//    before writing (ovf normally empty -> only waves with dtrue > MAXD scan it).
//    out[d][c] = rsqrt(deg_d) * sum_p rsqrt(deg_sp) * Ybf[sp][c] + b[c]
__global__ __launch_bounds__(256) void k_agg(const int* __restrict__ deg,
                                             const int* __restrict__ slot,
                                             const ushort* __restrict__ Ybf,
                                             const float* __restrict__ b,
                                             const int* __restrict__ src,
                                             const int* __restrict__ dst,
                                             const int* __restrict__ ovf,
                                             const int* __restrict__ ovf_cnt,
                                             float* __restrict__ out, int n) {
    int wid = (int)((blockIdx.x * (size_t)blockDim.x + threadIdx.x) >> 6);
    if (wid >= n) return;
    int lane = threadIdx.x & 63;
    int g = lane >> 4;        // edge slot 0..3
    int c = (lane & 15) * 4;  // column base (16 lanes x 4 cols = 64)
    int dtrue = deg[wid];     // wave-uniform broadcast load
    int dcnt = min(dtrue, MAXD);
    int s = wid * MAXD;
    int e = s + dcnt;
    float a0x = 0.f, a0y = 0.f, a0z = 0.f, a0w = 0.f;
    float a1x = 0.f, a1y = 0.f, a1z = 0.f, a1w = 0.f;
    int p = s + g;
    for (; p + 4 < e; p += 8) {
        int s0 = slot[p];
        int s1 = slot[p + 4];
        float f0 = rsqrtf(fmaxf((float)deg[s0], 1.0f));
        float f1 = rsqrtf(fmaxf((float)deg[s1], 1.0f));
        uint2 v0 = *(const uint2*)(Ybf + (size_t)s0 * N_CLS + c);  // 4 bf16 cols
        uint2 v1 = *(const uint2*)(Ybf + (size_t)s1 * N_CLS + c);
        a0x = fmaf(f0, __uint_as_float(v0.x << 16), a0x);
        a0y = fmaf(f0, __uint_as_float(v0.x & 0xFFFF0000u), a0y);
        a0z = fmaf(f0, __uint_as_float(v0.y << 16), a0z);
        a0w = fmaf(f0, __uint_as_float(v0.y & 0xFFFF0000u), a0w);
        a1x = fmaf(f1, __uint_as_float(v1.x << 16), a1x);
        a1y = fmaf(f1, __uint_as_float(v1.x & 0xFFFF0000u), a1y);
        a1z = fmaf(f1, __uint_as_float(v1.y << 16), a1z);
        a1w = fmaf(f1, __uint_as_float(v1.y & 0xFFFF0000u), a1w);
    }
    if (p < e) {
        int s0 = slot[p];
        float f0 = rsqrtf(fmaxf((float)deg[s0], 1.0f));
        uint2 v0 = *(const uint2*)(Ybf + (size_t)s0 * N_CLS + c);
        a0x = fmaf(f0, __uint_as_float(v0.x << 16), a0x);
        a0y = fmaf(f0, __uint_as_float(v0.x & 0xFFFF0000u), a0y);
        a0z = fmaf(f0, __uint_as_float(v0.y << 16), a0z);
        a0w = fmaf(f0, __uint_as_float(v0.y & 0xFFFF0000u), a0w);
    }
    // overflow fold-in (only for overflowed dsts; normally never taken)
    if (dtrue > MAXD) {
        int cnt = min(*ovf_cnt, 4096);
        for (int idx = 0; idx < cnt; ++idx) {
            int ei = ovf[idx];
            if (dst[ei] == wid && g == 0) {
                int s0 = src[ei];
                float f0 = rsqrtf(fmaxf((float)deg[s0], 1.0f));
                uint2 v0 = *(const uint2*)(Ybf + (size_t)s0 * N_CLS + c);
                a0x = fmaf(f0, __uint_as_float(v0.x << 16), a0x);
                a0y = fmaf(f0, __uint_as_float(v0.x & 0xFFFF0000u), a0y);
                a0z = fmaf(f0, __uint_as_float(v0.y << 16), a0z);
                a0w = fmaf(f0, __uint_as_float(v0.y & 0xFFFF0000u), a0w);
            }
        }
    }
    a0x += a1x; a0y += a1y; a0z += a1z; a0w += a1w;
#pragma unroll
    for (int m = 16; m <= 32; m <<= 1) {
        a0x += __shfl_xor(a0x, m);
        a0y += __shfl_xor(a0y, m);
        a0z += __shfl_xor(a0z, m);
        a0w += __shfl_xor(a0w, m);
    }
    if (lane < 16) {
        float nv = rsqrtf(fmaxf((float)dtrue, 1.0f));
        float4 bv = *(const float4*)(b + c);
        float4 o;
        o.x = a0x * nv + bv.x;
        o.y = a0y * nv + bv.y;
        o.z = a0z * nv + bv.z;
        o.w = a0w * nv + bv.w;
        *(float4*)(out + (size_t)wid * N_CLS + c) = o;
    }
}

extern "C" void kernel_launch(void* const* d_in, const int* in_sizes, int n_in,
                              void* d_out, int out_size, void* d_ws, size_t ws_size,
                              hipStream_t stream) {
    const float* X = (const float*)d_in[0];
    const float* W = (const float*)d_in[1];
    const float* b = (const float*)d_in[2];
    const int* src = (const int*)d_in[3];
    const int* dst = (const int*)d_in[4];
    int n = in_sizes[0] / N_FEAT;
    int ne = in_sizes[3];
    float* out = (float*)d_out;

    char* w = (char*)d_ws;
    auto take = [&](size_t bytes) {
        char* p = w;
        w += (bytes + 255) & ~(size_t)255;
        return p;
    };
    int* deg = (int*)take(((size_t)n + 4) * 4);      // 200KB dense counters
    int* slot = (int*)take((size_t)n * MAXD * 4);    // 12.8MB buckets
    int* rank = (int*)take((size_t)ne * 4);
    int* ovf = (int*)take((size_t)4096 * 4);
    int* ovf_cnt = (int*)take(256);
    ushort* Ybf = (ushort*)take((size_t)n * N_CLS * 2);  // 6.4MB bf16 Y

    const int tb = 256;
    int n4 = (n + 3) / 4;
    k_zero<<<(n4 + tb - 1) / tb, tb, 0, stream>>>((int4*)deg, n4, ovf_cnt);

    int gemm_blocks = (n + 63) / 64;        // 782
    int ne2 = (ne + 1) / 2;
    int rank_blocks = (ne2 + tb - 1) / tb;  // 1563
    k_fused1<<<gemm_blocks + rank_blocks, tb, 0, stream>>>(X, W, Ybf, n, dst, ne, deg, rank,
                                                           gemm_blocks);

    k_scat<<<(ne2 + tb - 1) / tb, tb, 0, stream>>>(src, dst, rank, ne, slot, ovf, ovf_cnt);

    long long agg_threads = (long long)n * 64;
    k_agg<<<(int)((agg_threads + tb - 1) / tb), tb, 0, stream>>>(deg, slot, Ybf, b, src, dst,
                                                                 ovf, ovf_cnt, out, n);
}

// Round 16
// 92.614 us; speedup vs baseline: 1.0311x; 1.0311x over previous
//
#include <hip/hip_runtime.h>
#include <hip/hip_bf16.h>

#define N_FEAT 128
#define N_CLS 64
#define MAXD 64      // bucket capacity; true max in-deg ~40 for Binomial(800K,1/50K)
#define DSTRIDE 16   // atomic counters padded to one per 64B line (proven +8%)

// 0) zero padded degree counters + overflow count (~800KB, ~2.5us)
__global__ __launch_bounds__(256) void k_zero(int4* __restrict__ p, int n4,
                                              int* __restrict__ ovf_cnt) {
    int i = blockIdx.x * blockDim.x + threadIdx.x;
    if (i < n4) p[i] = make_int4(0, 0, 0, 0);
    if (blockIdx.x == 0 && threadIdx.x == 0) *ovf_cnt = 0;
}

// 1) FUSED: blocks [0, gemm_blocks) = GEMM Ybf = bf16(X @ W) (wave-uniform W cols
//    -> s_load K$ broadcast). Remaining blocks = rank (atomic histogram, 2/thread,
//    padded counters).
__global__ __launch_bounds__(256) void k_fused1(
    const float* __restrict__ X, const float* __restrict__ W, ushort* __restrict__ Ybf, int n,
    const int* __restrict__ dst, int ne, int* __restrict__ deg16, int* __restrict__ rank,
    int gemm_blocks) {
    int bid = blockIdx.x;
    if (bid < gemm_blocks) {
        int lane = threadIdx.x & 63;
        int q = __builtin_amdgcn_readfirstlane(threadIdx.x >> 6);  // wave 0..3
        int cq = q * 16;
        int node = bid * 64 + lane;
        if (node >= n) return;

        float acc[16];
#pragma unroll
        for (int c = 0; c < 16; ++c) acc[c] = 0.f;

        const float* xrow = X + (size_t)node * N_FEAT;
        const float* wq = W + cq;
        for (int k4 = 0; k4 < N_FEAT; k4 += 4) {
            float4 xv = *(const float4*)(xrow + k4);
#pragma unroll
            for (int j = 0; j < 4; ++j) {
                float xj = (j == 0) ? xv.x : (j == 1) ? xv.y : (j == 2) ? xv.z : xv.w;
                const float* wrow = wq + (size_t)(k4 + j) * N_CLS;  // wave-uniform
#pragma unroll
                for (int c = 0; c < 16; c += 4) {
                    float4 wv = *(const float4*)(wrow + c);
                    acc[c + 0] = fmaf(xj, wv.x, acc[c + 0]);
                    acc[c + 1] = fmaf(xj, wv.y, acc[c + 1]);
                    acc[c + 2] = fmaf(xj, wv.z, acc[c + 2]);
                    acc[c + 3] = fmaf(xj, wv.w, acc[c + 3]);
                }
            }
        }

        // RNE-convert 16 fp32 -> bf16, pack to 2x uint4, store 32B
        uint u[8];
#pragma unroll
        for (int h = 0; h < 8; ++h) {
            __hip_bfloat16 lo = __float2bfloat16(acc[2 * h]);
            __hip_bfloat16 hi = __float2bfloat16(acc[2 * h + 1]);
            ushort ulo = *(ushort*)&lo;
            ushort uhi = *(ushort*)&hi;
            u[h] = ((uint)uhi << 16) | ulo;
        }
        ushort* yrow = Ybf + (size_t)node * N_CLS + cq;
        *(uint4*)(yrow + 0) = make_uint4(u[0], u[1], u[2], u[3]);
        *(uint4*)(yrow + 8) = make_uint4(u[4], u[5], u[6], u[7]);
    } else {
        int e2 = ((bid - gemm_blocks) * 256 + threadIdx.x) * 2;
        if (e2 + 1 < ne) {
            int2 d = *(const int2*)(dst + e2);
            int p0 = atomicAdd(&deg16[d.x * DSTRIDE], 1);  // two independent chains
            int p1 = atomicAdd(&deg16[d.y * DSTRIDE], 1);
            *(int2*)(rank + e2) = make_int2(p0, p1);
        } else if (e2 < ne) {
            rank[e2] = atomicAdd(&deg16[dst[e2] * DSTRIDE], 1);
        }
    }
}

// 2) FUSED: scatter blocks (slot[dst*MAXD+rank]=src, no hot-path atomics) +
//    compact blocks (deg[i] = deg16[i*DSTRIDE] -> dense 200KB for agg)
__global__ __launch_bounds__(256) void k_scat(const int* __restrict__ src,
                                              const int* __restrict__ dst,
                                              const int* __restrict__ rank, int ne,
                                              int* __restrict__ slot, int* __restrict__ ovf,
                                              int* __restrict__ ovf_cnt,
                                              const int* __restrict__ deg16, int n,
                                              int* __restrict__ deg, int scat_blocks) {
    int bid = blockIdx.x;
    if (bid < scat_blocks) {
        int e2 = (bid * 256 + threadIdx.x) * 2;
#pragma unroll
        for (int j = 0; j < 2; ++j) {
            int i = e2 + j;
            if (i < ne) {
                int p = rank[i];
                if (p < MAXD) {
                    slot[(size_t)dst[i] * MAXD + p] = src[i];
                } else {
                    ovf[atomicAdd(ovf_cnt, 1) & 4095] = i;  // never expected; gutter
                }
            }
        }
    } else {
        int i = (bid - scat_blocks) * 256 + threadIdx.x;
        if (i < n) deg[i] = deg16[i * DSTRIDE];
    }
}

// 3) wave-per-dst gather over buckets, bf16 Y rows (128B/row), on-the-fly rsqrt
//    from dense deg (200KB, L2-resident). Owner-wave folds any overflow edges in.
//    out[d][c] = rsqrt(deg_d) * sum_p rsqrt(deg_sp) * Ybf[sp][c] + b[c]
__global__ __launch_bounds__(256) void k_agg(const int* __restrict__ deg,
                                             const int* __restrict__ slot,
                                             const ushort* __restrict__ Ybf,
                                             const float* __restrict__ b,
                                             const int* __restrict__ src,
                                             const int* __restrict__ dst,
                                             const int* __restrict__ ovf,
                                             const int* __restrict__ ovf_cnt,
                                             float* __restrict__ out, int n) {
    int wid = (int)((blockIdx.x * (size_t)blockDim.x + threadIdx.x) >> 6);
    if (wid >= n) return;
    int lane = threadIdx.x & 63;
    int g = lane >> 4;        // edge slot 0..3
    int c = (lane & 15) * 4;  // column base (16 lanes x 4 cols = 64)
    int dtrue = deg[wid];     // wave-uniform broadcast load
    int dcnt = min(dtrue, MAXD);
    int s = wid * MAXD;
    int e = s + dcnt;
    float a0x = 0.f, a0y = 0.f, a0z = 0.f, a0w = 0.f;
    float a1x = 0.f, a1y = 0.f, a1z = 0.f, a1w = 0.f;
    int p = s + g;
    for (; p + 4 < e; p += 8) {
        int s0 = slot[p];
        int s1 = slot[p + 4];
        float f0 = rsqrtf(fmaxf((float)deg[s0], 1.0f));
        float f1 = rsqrtf(fmaxf((float)deg[s1], 1.0f));
        uint2 v0 = *(const uint2*)(Ybf + (size_t)s0 * N_CLS + c);  // 4 bf16 cols
        uint2 v1 = *(const uint2*)(Ybf + (size_t)s1 * N_CLS + c);
        a0x = fmaf(f0, __uint_as_float(v0.x << 16), a0x);
        a0y = fmaf(f0, __uint_as_float(v0.x & 0xFFFF0000u), a0y);
        a0z = fmaf(f0, __uint_as_float(v0.y << 16), a0z);
        a0w = fmaf(f0, __uint_as_float(v0.y & 0xFFFF0000u), a0w);
        a1x = fmaf(f1, __uint_as_float(v1.x << 16), a1x);
        a1y = fmaf(f1, __uint_as_float(v1.x & 0xFFFF0000u), a1y);
        a1z = fmaf(f1, __uint_as_float(v1.y << 16), a1z);
        a1w = fmaf(f1, __uint_as_float(v1.y & 0xFFFF0000u), a1w);
    }
    if (p < e) {
        int s0 = slot[p];
        float f0 = rsqrtf(fmaxf((float)deg[s0], 1.0f));
        uint2 v0 = *(const uint2*)(Ybf + (size_t)s0 * N_CLS + c);
        a0x = fmaf(f0, __uint_as_float(v0.x << 16), a0x);
        a0y = fmaf(f0, __uint_as_float(v0.x & 0xFFFF0000u), a0y);
        a0z = fmaf(f0, __uint_as_float(v0.y << 16), a0z);
        a0w = fmaf(f0, __uint_as_float(v0.y & 0xFFFF0000u), a0w);
    }
    // overflow fold-in (only for overflowed dsts; normally never taken)
    if (dtrue > MAXD) {
        int cnt = min(*ovf_cnt, 4096);
        for (int idx = 0; idx < cnt; ++idx) {
            int ei = ovf[idx];
            if (dst[ei] == wid && g == 0) {
                int s0 = src[ei];
                float f0 = rsqrtf(fmaxf((float)deg[s0], 1.0f));
                uint2 v0 = *(const uint2*)(Ybf + (size_t)s0 * N_CLS + c);
                a0x = fmaf(f0, __uint_as_float(v0.x << 16), a0x);
                a0y = fmaf(f0, __uint_as_float(v0.x & 0xFFFF0000u), a0y);
                a0z = fmaf(f0, __uint_as_float(v0.y << 16), a0z);
                a0w = fmaf(f0, __uint_as_float(v0.y & 0xFFFF0000u), a0w);
            }
        }
    }
    a0x += a1x; a0y += a1y; a0z += a1z; a0w += a1w;
#pragma unroll
    for (int m = 16; m <= 32; m <<= 1) {
        a0x += __shfl_xor(a0x, m);
        a0y += __shfl_xor(a0y, m);
        a0z += __shfl_xor(a0z, m);
        a0w += __shfl_xor(a0w, m);
    }
    if (lane < 16) {
        float nv = rsqrtf(fmaxf((float)dtrue, 1.0f));
        float4 bv = *(const float4*)(b + c);
        float4 o;
        o.x = a0x * nv + bv.x;
        o.y = a0y * nv + bv.y;
        o.z = a0z * nv + bv.z;
        o.w = a0w * nv + bv.w;
        *(float4*)(out + (size_t)wid * N_CLS + c) = o;
    }
}

extern "C" void kernel_launch(void* const* d_in, const int* in_sizes, int n_in,
                              void* d_out, int out_size, void* d_ws, size_t ws_size,
                              hipStream_t stream) {
    const float* X = (const float*)d_in[0];
    const float* W = (const float*)d_in[1];
    const float* b = (const float*)d_in[2];
    const int* src = (const int*)d_in[3];
    const int* dst = (const int*)d_in[4];
    int n = in_sizes[0] / N_FEAT;
    int ne = in_sizes[3];
    float* out = (float*)d_out;

    char* w = (char*)d_ws;
    auto take = [&](size_t bytes) {
        char* p = w;
        w += (bytes + 255) & ~(size_t)255;
        return p;
    };
    int* deg16 = (int*)take((size_t)n * DSTRIDE * 4);  // 3.2MB padded counters
    int* deg = (int*)take((size_t)n * 4);              // 200KB dense (for agg)
    int* slot = (int*)take((size_t)n * MAXD * 4);      // 12.8MB buckets
    int* rank = (int*)take((size_t)ne * 4);
    int* ovf = (int*)take((size_t)4096 * 4);
    int* ovf_cnt = (int*)take(256);
    ushort* Ybf = (ushort*)take((size_t)n * N_CLS * 2);  // 6.4MB bf16 Y

    const int tb = 256;
    int n4 = (n * DSTRIDE + 3) / 4;
    k_zero<<<(n4 + tb - 1) / tb, tb, 0, stream>>>((int4*)deg16, n4, ovf_cnt);

    int gemm_blocks = (n + 63) / 64;        // 782
    int ne2 = (ne + 1) / 2;
    int rank_blocks = (ne2 + tb - 1) / tb;  // 1563
    k_fused1<<<gemm_blocks + rank_blocks, tb, 0, stream>>>(X, W, Ybf, n, dst, ne, deg16, rank,
                                                           gemm_blocks);

    int scat_blocks = (ne2 + tb - 1) / tb;  // 1563
    int cmp_blocks = (n + tb - 1) / tb;     // 196
    k_scat<<<scat_blocks + cmp_blocks, tb, 0, stream>>>(src, dst, rank, ne, slot, ovf, ovf_cnt,
                                                        deg16, n, deg, scat_blocks);

    long long agg_threads = (long long)n * 64;
    k_agg<<<(int)((agg_threads + tb - 1) / tb), tb, 0, stream>>>(deg, slot, Ybf, b, src, dst,
                                                                 ovf, ovf_cnt, out, n);
}

// Round 17
// 70.453 us; speedup vs baseline: 1.3554x; 1.3145x over previous
//
#include <hip/hip_runtime.h>
#include <hip/hip_bf16.h>

#define N_FEAT 128
#define N_CLS 64
#define MAXD 64        // per-dst slot capacity; true max in-deg ~40
#define BINW 512       // dsts per coarse bin (bin = dst >> 9)
#define NBINS_MAX 128  // 50000/512 = 98 bins
#define CAP 16384      // coarse bin capacity (mean ~8163, +80 sigma)
#define OVCAP 8192

// 0) zero bin cursors + gutter counters (~520B, one block)
__global__ __launch_bounds__(256) void k_zero(int* __restrict__ ccur, int nbins,
                                              int* __restrict__ ovfA_cnt,
                                              int* __restrict__ ovfB_cnt) {
    int t = threadIdx.x;
    if (t < nbins) ccur[t] = 0;
    if (t == 0) { *ovfA_cnt = 0; *ovfB_cnt = 0; }
}

// 1) FUSED: blocks [0, gemm_blocks) = GEMM Ybf = bf16(X @ W) (wave-uniform W cols
//    -> s_load K$ broadcast). Remaining blocks = coarse binning: 2048 edges/block,
//    LDS histogram over 98 bins + ONE global atomic per touched bin (38K total,
//    21x fewer than per-edge), then grouped (dst,src) writes into bin regions.
__global__ __launch_bounds__(256) void k_fused(
    const float* __restrict__ X, const float* __restrict__ W, ushort* __restrict__ Ybf, int n,
    const int* __restrict__ src, const int* __restrict__ dst, int ne,
    int* __restrict__ ccur, int2* __restrict__ coarse, int2* __restrict__ ovfA,
    int* __restrict__ ovfA_cnt, int gemm_blocks) {
    __shared__ int hist[NBINS_MAX];
    __shared__ int base[NBINS_MAX];
    int bid = blockIdx.x;
    if (bid < gemm_blocks) {
        int lane = threadIdx.x & 63;
        int q = __builtin_amdgcn_readfirstlane(threadIdx.x >> 6);  // wave 0..3
        int cq = q * 16;
        int node = bid * 64 + lane;
        if (node >= n) return;

        float acc[16];
#pragma unroll
        for (int c = 0; c < 16; ++c) acc[c] = 0.f;

        const float* xrow = X + (size_t)node * N_FEAT;
        const float* wq = W + cq;
        for (int k4 = 0; k4 < N_FEAT; k4 += 4) {
            float4 xv = *(const float4*)(xrow + k4);
#pragma unroll
            for (int j = 0; j < 4; ++j) {
                float xj = (j == 0) ? xv.x : (j == 1) ? xv.y : (j == 2) ? xv.z : xv.w;
                const float* wrow = wq + (size_t)(k4 + j) * N_CLS;  // wave-uniform
#pragma unroll
                for (int c = 0; c < 16; c += 4) {
                    float4 wv = *(const float4*)(wrow + c);
                    acc[c + 0] = fmaf(xj, wv.x, acc[c + 0]);
                    acc[c + 1] = fmaf(xj, wv.y, acc[c + 1]);
                    acc[c + 2] = fmaf(xj, wv.z, acc[c + 2]);
                    acc[c + 3] = fmaf(xj, wv.w, acc[c + 3]);
                }
            }
        }

        uint u[8];
#pragma unroll
        for (int h = 0; h < 8; ++h) {
            __hip_bfloat16 lo = __float2bfloat16(acc[2 * h]);
            __hip_bfloat16 hi = __float2bfloat16(acc[2 * h + 1]);
            ushort ulo = *(ushort*)&lo;
            ushort uhi = *(ushort*)&hi;
            u[h] = ((uint)uhi << 16) | ulo;
        }
        ushort* yrow = Ybf + (size_t)node * N_CLS + cq;
        *(uint4*)(yrow + 0) = make_uint4(u[0], u[1], u[2], u[3]);
        *(uint4*)(yrow + 8) = make_uint4(u[4], u[5], u[6], u[7]);
    } else {
        int rb = bid - gemm_blocks;
        int t = threadIdx.x;
        for (int i = t; i < NBINS_MAX; i += 256) hist[i] = 0;
        __syncthreads();
        int e0 = rb * 2048;
        int d[8], s[8], lr[8];
#pragma unroll
        for (int j = 0; j < 8; ++j) {
            int i = e0 + j * 256 + t;
            lr[j] = -1;
            d[j] = 0;
            s[j] = 0;
            if (i < ne) {
                d[j] = dst[i];
                s[j] = src[i];
                lr[j] = atomicAdd(&hist[d[j] >> 9], 1);  // LDS atomic, cheap
            }
        }
        __syncthreads();
        for (int i = t; i < NBINS_MAX; i += 256) {
            int h = hist[i];
            base[i] = h ? atomicAdd(&ccur[i], h) : 0;  // 1 global atomic per bin
        }
        __syncthreads();
#pragma unroll
        for (int j = 0; j < 8; ++j) {
            if (lr[j] >= 0) {
                int bn = d[j] >> 9;
                int pos = base[bn] + lr[j];
                if (pos < CAP) {
                    coarse[(size_t)bn * CAP + pos] = make_int2(d[j], s[j]);
                } else {
                    int o = atomicAdd(ovfA_cnt, 1);  // never expected; gutter
                    if (o < OVCAP) ovfA[o] = make_int2(d[j], s[j]);
                }
            }
        }
    }
}

// 2) fine binning: one 1024-thread block per coarse bin. LDS 512-counter fine
//    histogram -> per-dst rank (LDS atomics, ZERO global atomics), scatter to
//    slot[dst*MAXD+r] (128KB L2-local window), write dense deg for the range.
__global__ __launch_bounds__(1024) void k_bins(
    const int* __restrict__ ccur, const int2* __restrict__ coarse,
    const int2* __restrict__ ovfA, const int* __restrict__ ovfA_cnt,
    int* __restrict__ deg, int* __restrict__ slot, int2* __restrict__ ovfB,
    int* __restrict__ ovfB_cnt, int n) {
    __shared__ int cnt[BINW];
    int q = blockIdx.x;
    int t = threadIdx.x;
    int dbase = q * BINW;
    if (t < BINW) cnt[t] = 0;
    __syncthreads();
    int tot = min(ccur[q], CAP);
    const int2* lst = coarse + (size_t)q * CAP;
    for (int i = t; i < tot; i += 1024) {
        int2 e = lst[i];
        int r = atomicAdd(&cnt[e.x - dbase], 1);
        if (r < MAXD) {
            slot[(size_t)e.x * MAXD + r] = e.y;
        } else {
            int o = atomicAdd(ovfB_cnt, 1);  // never expected; gutter
            if (o < OVCAP) ovfB[o] = e;
        }
    }
    int oa = *ovfA_cnt;
    if (oa > 0) {  // fold pass-A gutter in (keeps deg exact); normally skipped
        oa = min(oa, OVCAP);
        for (int i = t; i < oa; i += 1024) {
            int2 e = ovfA[i];
            if (e.x >= dbase && e.x < dbase + BINW) {
                int r = atomicAdd(&cnt[e.x - dbase], 1);
                if (r < MAXD) {
                    slot[(size_t)e.x * MAXD + r] = e.y;
                } else {
                    int o = atomicAdd(ovfB_cnt, 1);
                    if (o < OVCAP) ovfB[o] = e;
                }
            }
        }
    }
    __syncthreads();
    int i = dbase + t;
    if (t < BINW && i < n) deg[i] = cnt[t];
}

// 3) wave-per-dst gather over buckets, bf16 Y rows, on-the-fly rsqrt from dense
//    deg (200KB, L2-resident). Owner-wave folds ovfB (dst,src) entries in.
//    out[d][c] = rsqrt(deg_d) * sum_p rsqrt(deg_sp) * Ybf[sp][c] + b[c]
__global__ __launch_bounds__(256) void k_agg(const int* __restrict__ deg,
                                             const int* __restrict__ slot,
                                             const ushort* __restrict__ Ybf,
                                             const float* __restrict__ b,
                                             const int2* __restrict__ ovfB,
                                             const int* __restrict__ ovfB_cnt,
                                             float* __restrict__ out, int n) {
    int wid = (int)((blockIdx.x * (size_t)blockDim.x + threadIdx.x) >> 6);
    if (wid >= n) return;
    int lane = threadIdx.x & 63;
    int g = lane >> 4;        // edge slot 0..3
    int c = (lane & 15) * 4;  // column base (16 lanes x 4 cols = 64)
    int dtrue = deg[wid];     // wave-uniform broadcast load
    int dcnt = min(dtrue, MAXD);
    int s = wid * MAXD;
    int e = s + dcnt;
    float a0x = 0.f, a0y = 0.f, a0z = 0.f, a0w = 0.f;
    float a1x = 0.f, a1y = 0.f, a1z = 0.f, a1w = 0.f;
    int p = s + g;
    for (; p + 4 < e; p += 8) {
        int s0 = slot[p];
        int s1 = slot[p + 4];
        float f0 = rsqrtf(fmaxf((float)deg[s0], 1.0f));
        float f1 = rsqrtf(fmaxf((float)deg[s1], 1.0f));
        uint2 v0 = *(const uint2*)(Ybf + (size_t)s0 * N_CLS + c);  // 4 bf16 cols
        uint2 v1 = *(const uint2*)(Ybf + (size_t)s1 * N_CLS + c);
        a0x = fmaf(f0, __uint_as_float(v0.x << 16), a0x);
        a0y = fmaf(f0, __uint_as_float(v0.x & 0xFFFF0000u), a0y);
        a0z = fmaf(f0, __uint_as_float(v0.y << 16), a0z);
        a0w = fmaf(f0, __uint_as_float(v0.y & 0xFFFF0000u), a0w);
        a1x = fmaf(f1, __uint_as_float(v1.x << 16), a1x);
        a1y = fmaf(f1, __uint_as_float(v1.x & 0xFFFF0000u), a1y);
        a1z = fmaf(f1, __uint_as_float(v1.y << 16), a1z);
        a1w = fmaf(f1, __uint_as_float(v1.y & 0xFFFF0000u), a1w);
    }
    if (p < e) {
        int s0 = slot[p];
        float f0 = rsqrtf(fmaxf((float)deg[s0], 1.0f));
        uint2 v0 = *(const uint2*)(Ybf + (size_t)s0 * N_CLS + c);
        a0x = fmaf(f0, __uint_as_float(v0.x << 16), a0x);
        a0y = fmaf(f0, __uint_as_float(v0.x & 0xFFFF0000u), a0y);
        a0z = fmaf(f0, __uint_as_float(v0.y << 16), a0z);
        a0w = fmaf(f0, __uint_as_float(v0.y & 0xFFFF0000u), a0w);
    }
    if (dtrue > MAXD) {  // slot-overflow fold-in; normally never taken
        int cnt2 = min(*ovfB_cnt, OVCAP);
        for (int idx = 0; idx < cnt2; ++idx) {
            int2 ev = ovfB[idx];
            if (ev.x == wid && g == 0) {
                int s0 = ev.y;
                float f0 = rsqrtf(fmaxf((float)deg[s0], 1.0f));
                uint2 v0 = *(const uint2*)(Ybf + (size_t)s0 * N_CLS + c);
                a0x = fmaf(f0, __uint_as_float(v0.x << 16), a0x);
                a0y = fmaf(f0, __uint_as_float(v0.x & 0xFFFF0000u), a0y);
                a0z = fmaf(f0, __uint_as_float(v0.y << 16), a0z);
                a0w = fmaf(f0, __uint_as_float(v0.y & 0xFFFF0000u), a0w);
            }
        }
    }
    a0x += a1x; a0y += a1y; a0z += a1z; a0w += a1w;
#pragma unroll
    for (int m = 16; m <= 32; m <<= 1) {
        a0x += __shfl_xor(a0x, m);
        a0y += __shfl_xor(a0y, m);
        a0z += __shfl_xor(a0z, m);
        a0w += __shfl_xor(a0w, m);
    }
    if (lane < 16) {
        float nv = rsqrtf(fmaxf((float)dtrue, 1.0f));
        float4 bv = *(const float4*)(b + c);
        float4 o;
        o.x = a0x * nv + bv.x;
        o.y = a0y * nv + bv.y;
        o.z = a0z * nv + bv.z;
        o.w = a0w * nv + bv.w;
        *(float4*)(out + (size_t)wid * N_CLS + c) = o;
    }
}

extern "C" void kernel_launch(void* const* d_in, const int* in_sizes, int n_in,
                              void* d_out, int out_size, void* d_ws, size_t ws_size,
                              hipStream_t stream) {
    const float* X = (const float*)d_in[0];
    const float* W = (const float*)d_in[1];
    const float* b = (const float*)d_in[2];
    const int* src = (const int*)d_in[3];
    const int* dst = (const int*)d_in[4];
    int n = in_sizes[0] / N_FEAT;
    int ne = in_sizes[3];
    float* out = (float*)d_out;

    char* w = (char*)d_ws;
    auto take = [&](size_t bytes) {
        char* p = w;
        w += (bytes + 255) & ~(size_t)255;
        return p;
    };
    int nbins = (n + BINW - 1) / BINW;  // 98
    int* ccur = (int*)take((size_t)NBINS_MAX * 4);
    int* ovfA_cnt = (int*)take(256);
    int* ovfB_cnt = (int*)take(256);
    int2* coarse = (int2*)take((size_t)nbins * CAP * 8);  // 12.8MB
    int2* ovfA = (int2*)take((size_t)OVCAP * 8);
    int2* ovfB = (int2*)take((size_t)OVCAP * 8);
    int* deg = (int*)take((size_t)n * 4);                 // 200KB dense
    int* slot = (int*)take((size_t)n * MAXD * 4);         // 12.8MB
    ushort* Ybf = (ushort*)take((size_t)n * N_CLS * 2);   // 6.4MB bf16 Y

    const int tb = 256;
    k_zero<<<1, tb, 0, stream>>>(ccur, nbins, ovfA_cnt, ovfB_cnt);

    int gemm_blocks = (n + 63) / 64;          // 782
    int binA_blocks = (ne + 2047) / 2048;     // 391
    k_fused<<<gemm_blocks + binA_blocks, tb, 0, stream>>>(X, W, Ybf, n, src, dst, ne, ccur,
                                                          coarse, ovfA, ovfA_cnt, gemm_blocks);

    k_bins<<<nbins, 1024, 0, stream>>>(ccur, coarse, ovfA, ovfA_cnt, deg, slot, ovfB, ovfB_cnt,
                                       n);

    long long agg_threads = (long long)n * 64;
    k_agg<<<(int)((agg_threads + tb - 1) / tb), tb, 0, stream>>>(deg, slot, Ybf, b, ovfB,
                                                                 ovfB_cnt, out, n);
}

// Round 18
// 70.095 us; speedup vs baseline: 1.3623x; 1.0051x over previous
//
#include <hip/hip_runtime.h>
#include <hip/hip_bf16.h>

#define N_FEAT 128
#define N_CLS 64
#define MAXD 64        // per-dst slot capacity; true max in-deg ~40
#define BINW 128       // dsts per coarse bin (bin = dst >> 7)
#define BSHIFT 7
#define NBINS_MAX 512  // 50000/128 = 391 bins
#define CAP 4096       // coarse bin capacity (mean ~2046, +45 sigma)
#define OVCAP 8192

// 0) zero bin cursors + gutter counters (one block)
__global__ __launch_bounds__(512) void k_zero(int* __restrict__ ccur, int nbins,
                                              int* __restrict__ ovfA_cnt,
                                              int* __restrict__ ovfB_cnt) {
    int t = threadIdx.x;
    if (t < nbins) ccur[t] = 0;
    if (t == 0) { *ovfA_cnt = 0; *ovfB_cnt = 0; }
}

// 1) FUSED, roles interleaved bid%3 ({0,1}=GEMM, {2}=binning; 782:391 = 2:1 so
//    both roles co-schedule across all CUs for the whole dispatch):
//    GEMM: Ybf = bf16(X @ W), wave-uniform W cols -> s_load K$ broadcast.
//    binA: 2048 edges/block, LDS hist over 391 bins + ONE global atomic per
//    touched bin (~38K total vs 800K per-edge), grouped (dst,src) region writes.
__global__ __launch_bounds__(256) void k_fused(
    const float* __restrict__ X, const float* __restrict__ W, ushort* __restrict__ Ybf, int n,
    const int* __restrict__ src, const int* __restrict__ dst, int ne,
    int* __restrict__ ccur, int2* __restrict__ coarse, int2* __restrict__ ovfA,
    int* __restrict__ ovfA_cnt, int gemm_blocks, int binA_blocks) {
    __shared__ int hist[NBINS_MAX];
    __shared__ int base[NBINS_MAX];
    int k = blockIdx.x;
    bool is_bin = (k % 3 == 2) && (k / 3 < binA_blocks);
    if (!is_bin) {
        int gb = k - min((k + 1) / 3, binA_blocks);  // gemm index among gemm blocks
        if (gb >= gemm_blocks) return;
        int lane = threadIdx.x & 63;
        int q = __builtin_amdgcn_readfirstlane(threadIdx.x >> 6);  // wave 0..3
        int cq = q * 16;
        int node = gb * 64 + lane;
        if (node >= n) return;

        float acc[16];
#pragma unroll
        for (int c = 0; c < 16; ++c) acc[c] = 0.f;

        const float* xrow = X + (size_t)node * N_FEAT;
        const float* wq = W + cq;
        for (int k4 = 0; k4 < N_FEAT; k4 += 4) {
            float4 xv = *(const float4*)(xrow + k4);
#pragma unroll
            for (int j = 0; j < 4; ++j) {
                float xj = (j == 0) ? xv.x : (j == 1) ? xv.y : (j == 2) ? xv.z : xv.w;
                const float* wrow = wq + (size_t)(k4 + j) * N_CLS;  // wave-uniform
#pragma unroll
                for (int c = 0; c < 16; c += 4) {
                    float4 wv = *(const float4*)(wrow + c);
                    acc[c + 0] = fmaf(xj, wv.x, acc[c + 0]);
                    acc[c + 1] = fmaf(xj, wv.y, acc[c + 1]);
                    acc[c + 2] = fmaf(xj, wv.z, acc[c + 2]);
                    acc[c + 3] = fmaf(xj, wv.w, acc[c + 3]);
                }
            }
        }

        uint u[8];
#pragma unroll
        for (int h = 0; h < 8; ++h) {
            __hip_bfloat16 lo = __float2bfloat16(acc[2 * h]);
            __hip_bfloat16 hi = __float2bfloat16(acc[2 * h + 1]);
            ushort ulo = *(ushort*)&lo;
            ushort uhi = *(ushort*)&hi;
            u[h] = ((uint)uhi << 16) | ulo;
        }
        ushort* yrow = Ybf + (size_t)node * N_CLS + cq;
        *(uint4*)(yrow + 0) = make_uint4(u[0], u[1], u[2], u[3]);
        *(uint4*)(yrow + 8) = make_uint4(u[4], u[5], u[6], u[7]);
    } else {
        int rb = k / 3;
        int t = threadIdx.x;
        for (int i = t; i < NBINS_MAX; i += 256) hist[i] = 0;
        __syncthreads();
        int e0 = rb * 2048;
        int d[8], s[8], lr[8];
#pragma unroll
        for (int j = 0; j < 8; ++j) {
            int i = e0 + j * 256 + t;
            lr[j] = -1;
            d[j] = 0;
            s[j] = 0;
            if (i < ne) {
                d[j] = dst[i];
                s[j] = src[i];
                lr[j] = atomicAdd(&hist[d[j] >> BSHIFT], 1);  // LDS atomic, cheap
            }
        }
        __syncthreads();
        for (int i = t; i < NBINS_MAX; i += 256) {
            int h = hist[i];
            base[i] = h ? atomicAdd(&ccur[i], h) : 0;  // 1 global atomic per bin
        }
        __syncthreads();
#pragma unroll
        for (int j = 0; j < 8; ++j) {
            if (lr[j] >= 0) {
                int bn = d[j] >> BSHIFT;
                int pos = base[bn] + lr[j];
                if (pos < CAP) {
                    coarse[(size_t)bn * CAP + pos] = make_int2(d[j], s[j]);
                } else {
                    int o = atomicAdd(ovfA_cnt, 1);  // never expected; gutter
                    if (o < OVCAP) ovfA[o] = make_int2(d[j], s[j]);
                }
            }
        }
    }
}

// 2) fine binning: one 512-thread block per coarse bin (391 blocks). LDS
//    128-counter fine histogram -> per-dst rank (zero global atomics), scatter
//    to slot[dst*MAXD+r], write dense deg for the range.
__global__ __launch_bounds__(512) void k_bins(
    const int* __restrict__ ccur, const int2* __restrict__ coarse,
    const int2* __restrict__ ovfA, const int* __restrict__ ovfA_cnt,
    int* __restrict__ deg, int* __restrict__ slot, int2* __restrict__ ovfB,
    int* __restrict__ ovfB_cnt, int n) {
    __shared__ int cnt[BINW];
    int q = blockIdx.x;
    int t = threadIdx.x;
    int dbase = q << BSHIFT;
    if (t < BINW) cnt[t] = 0;
    __syncthreads();
    int tot = min(ccur[q], CAP);
    const int2* lst = coarse + (size_t)q * CAP;
    for (int i = t; i < tot; i += 512) {
        int2 e = lst[i];
        int r = atomicAdd(&cnt[e.x - dbase], 1);
        if (r < MAXD) {
            slot[(size_t)e.x * MAXD + r] = e.y;
        } else {
            int o = atomicAdd(ovfB_cnt, 1);  // never expected; gutter
            if (o < OVCAP) ovfB[o] = e;
        }
    }
    int oa = *ovfA_cnt;
    if (oa > 0) {  // fold pass-A gutter in (keeps deg exact); normally skipped
        oa = min(oa, OVCAP);
        for (int i = t; i < oa; i += 512) {
            int2 e = ovfA[i];
            if (e.x >= dbase && e.x < dbase + BINW) {
                int r = atomicAdd(&cnt[e.x - dbase], 1);
                if (r < MAXD) {
                    slot[(size_t)e.x * MAXD + r] = e.y;
                } else {
                    int o = atomicAdd(ovfB_cnt, 1);
                    if (o < OVCAP) ovfB[o] = e;
                }
            }
        }
    }
    __syncthreads();
    int i = dbase + t;
    if (t < BINW && i < n) deg[i] = cnt[t];
}

// 3) wave-per-dst gather over buckets, bf16 Y rows, on-the-fly rsqrt from dense
//    deg (200KB, L2-resident). Owner-wave folds ovfB (dst,src) entries in.
//    out[d][c] = rsqrt(deg_d) * sum_p rsqrt(deg_sp) * Ybf[sp][c] + b[c]
__global__ __launch_bounds__(256) void k_agg(const int* __restrict__ deg,
                                             const int* __restrict__ slot,
                                             const ushort* __restrict__ Ybf,
                                             const float* __restrict__ b,
                                             const int2* __restrict__ ovfB,
                                             const int* __restrict__ ovfB_cnt,
                                             float* __restrict__ out, int n) {
    int wid = (int)((blockIdx.x * (size_t)blockDim.x + threadIdx.x) >> 6);
    if (wid >= n) return;
    int lane = threadIdx.x & 63;
    int g = lane >> 4;        // edge slot 0..3
    int c = (lane & 15) * 4;  // column base (16 lanes x 4 cols = 64)
    int dtrue = deg[wid];     // wave-uniform broadcast load
    int dcnt = min(dtrue, MAXD);
    int s = wid * MAXD;
    int e = s + dcnt;
    float a0x = 0.f, a0y = 0.f, a0z = 0.f, a0w = 0.f;
    float a1x = 0.f, a1y = 0.f, a1z = 0.f, a1w = 0.f;
    int p = s + g;
    for (; p + 4 < e; p += 8) {
        int s0 = slot[p];
        int s1 = slot[p + 4];
        float f0 = rsqrtf(fmaxf((float)deg[s0], 1.0f));
        float f1 = rsqrtf(fmaxf((float)deg[s1], 1.0f));
        uint2 v0 = *(const uint2*)(Ybf + (size_t)s0 * N_CLS + c);  // 4 bf16 cols
        uint2 v1 = *(const uint2*)(Ybf + (size_t)s1 * N_CLS + c);
        a0x = fmaf(f0, __uint_as_float(v0.x << 16), a0x);
        a0y = fmaf(f0, __uint_as_float(v0.x & 0xFFFF0000u), a0y);
        a0z = fmaf(f0, __uint_as_float(v0.y << 16), a0z);
        a0w = fmaf(f0, __uint_as_float(v0.y & 0xFFFF0000u), a0w);
        a1x = fmaf(f1, __uint_as_float(v1.x << 16), a1x);
        a1y = fmaf(f1, __uint_as_float(v1.x & 0xFFFF0000u), a1y);
        a1z = fmaf(f1, __uint_as_float(v1.y << 16), a1z);
        a1w = fmaf(f1, __uint_as_float(v1.y & 0xFFFF0000u), a1w);
    }
    if (p < e) {
        int s0 = slot[p];
        float f0 = rsqrtf(fmaxf((float)deg[s0], 1.0f));
        uint2 v0 = *(const uint2*)(Ybf + (size_t)s0 * N_CLS + c);
        a0x = fmaf(f0, __uint_as_float(v0.x << 16), a0x);
        a0y = fmaf(f0, __uint_as_float(v0.x & 0xFFFF0000u), a0y);
        a0z = fmaf(f0, __uint_as_float(v0.y << 16), a0z);
        a0w = fmaf(f0, __uint_as_float(v0.y & 0xFFFF0000u), a0w);
    }
    if (dtrue > MAXD) {  // slot-overflow fold-in; normally never taken
        int cnt2 = min(*ovfB_cnt, OVCAP);
        for (int idx = 0; idx < cnt2; ++idx) {
            int2 ev = ovfB[idx];
            if (ev.x == wid && g == 0) {
                int s0 = ev.y;
                float f0 = rsqrtf(fmaxf((float)deg[s0], 1.0f));
                uint2 v0 = *(const uint2*)(Ybf + (size_t)s0 * N_CLS + c);
                a0x = fmaf(f0, __uint_as_float(v0.x << 16), a0x);
                a0y = fmaf(f0, __uint_as_float(v0.x & 0xFFFF0000u), a0y);
                a0z = fmaf(f0, __uint_as_float(v0.y << 16), a0z);
                a0w = fmaf(f0, __uint_as_float(v0.y & 0xFFFF0000u), a0w);
            }
        }
    }
    a0x += a1x; a0y += a1y; a0z += a1z; a0w += a1w;
#pragma unroll
    for (int m = 16; m <= 32; m <<= 1) {
        a0x += __shfl_xor(a0x, m);
        a0y += __shfl_xor(a0y, m);
        a0z += __shfl_xor(a0z, m);
        a0w += __shfl_xor(a0w, m);
    }
    if (lane < 16) {
        float nv = rsqrtf(fmaxf((float)dtrue, 1.0f));
        float4 bv = *(const float4*)(b + c);
        float4 o;
        o.x = a0x * nv + bv.x;
        o.y = a0y * nv + bv.y;
        o.z = a0z * nv + bv.z;
        o.w = a0w * nv + bv.w;
        *(float4*)(out + (size_t)wid * N_CLS + c) = o;
    }
}

extern "C" void kernel_launch(void* const* d_in, const int* in_sizes, int n_in,
                              void* d_out, int out_size, void* d_ws, size_t ws_size,
                              hipStream_t stream) {
    const float* X = (const float*)d_in[0];
    const float* W = (const float*)d_in[1];
    const float* b = (const float*)d_in[2];
    const int* src = (const int*)d_in[3];
    const int* dst = (const int*)d_in[4];
    int n = in_sizes[0] / N_FEAT;
    int ne = in_sizes[3];
    float* out = (float*)d_out;

    char* w = (char*)d_ws;
    auto take = [&](size_t bytes) {
        char* p = w;
        w += (bytes + 255) & ~(size_t)255;
        return p;
    };
    int nbins = (n + BINW - 1) / BINW;  // 391
    int* ccur = (int*)take((size_t)NBINS_MAX * 4);
    int* ovfA_cnt = (int*)take(256);
    int* ovfB_cnt = (int*)take(256);
    int2* coarse = (int2*)take((size_t)nbins * CAP * 8);  // 12.8MB
    int2* ovfA = (int2*)take((size_t)OVCAP * 8);
    int2* ovfB = (int2*)take((size_t)OVCAP * 8);
    int* deg = (int*)take((size_t)n * 4);                 // 200KB dense
    int* slot = (int*)take((size_t)n * MAXD * 4);         // 12.8MB
    ushort* Ybf = (ushort*)take((size_t)n * N_CLS * 2);   // 6.4MB bf16 Y

    const int tb = 256;
    k_zero<<<1, 512, 0, stream>>>(ccur, nbins, ovfA_cnt, ovfB_cnt);

    int gemm_blocks = (n + 63) / 64;          // 782
    int binA_blocks = (ne + 2047) / 2048;     // 391
    k_fused<<<gemm_blocks + binA_blocks, tb, 0, stream>>>(X, W, Ybf, n, src, dst, ne, ccur,
                                                          coarse, ovfA, ovfA_cnt, gemm_blocks,
                                                          binA_blocks);

    k_bins<<<nbins, 512, 0, stream>>>(ccur, coarse, ovfA, ovfA_cnt, deg, slot, ovfB, ovfB_cnt,
                                      n);

    long long agg_threads = (long long)n * 64;
    k_agg<<<(int)((agg_threads + tb - 1) / tb), tb, 0, stream>>>(deg, slot, Ybf, b, ovfB,
                                                                 ovfB_cnt, out, n);
}